// Round 5
// baseline (351.598 us; speedup 1.0000x reference)
//
#include <hip/hip_runtime.h>

#define SEQ 4096
#define DIM 128
#define BK 32
#define KSTR 136   // 128+8 fp16; row 272 B
#define VSTR 40    // 32+8;  row 80 B
#define PSTR 40
#define VSTRP 72   // prepass transpose tile stride (64 keys + 8)
#define PAIR_LDS (BK * KSTR * 2 + DIM * VSTR * 2)   // 8704 + 10240 = 18944 B
#define OSTR 132   // epilogue Obuf stride (floats)

// workspace: fp16 K + fp16 V-transposed only
#define KH_SZ  (8ull * SEQ * DIM * 2)
#define VT_OFF KH_SZ

typedef __attribute__((ext_vector_type(8))) _Float16 half8;
typedef __attribute__((ext_vector_type(2))) __fp16   fp16x2;
typedef __attribute__((ext_vector_type(4))) float  float4v;
typedef __attribute__((ext_vector_type(4))) unsigned int uint4v;

static __device__ __forceinline__ unsigned int pkh(float a, float b) {
    fp16x2 h = __builtin_amdgcn_cvt_pkrtz(a, b);
    return __builtin_bit_cast(unsigned int, h);
}

// ---------------- prepass: K -> fp16 [b][s][d], V -> fp16 transposed [b][d][s] ----------------
__global__ __launch_bounds__(256)
void prepass(const float* __restrict__ Kg, const float* __restrict__ Vg,
             short* __restrict__ Kh, short* __restrict__ VtG) {
    __shared__ short Ts[DIM * VSTRP];
    const int t  = threadIdx.x;
    const int b  = blockIdx.x & 7;
    const int s0 = (blockIdx.x >> 3) * 64;

    {   // K tile: 64 rows x 128 fp32 -> fp16
        const float4v* src = (const float4v*)(Kg + ((size_t)b * SEQ + s0) * DIM);
        uint4v* dst = (uint4v*)(Kh + ((size_t)b * SEQ + s0) * DIM);
        #pragma unroll
        for (int j = 0; j < 4; ++j) {
            int idx = j * 256 + t;
            float4v x0 = src[idx * 2];
            float4v x1 = src[idx * 2 + 1];
            uint4v u;
            u[0] = pkh(x0[0], x0[1]); u[1] = pkh(x0[2], x0[3]);
            u[2] = pkh(x1[0], x1[1]); u[3] = pkh(x1[2], x1[3]);
            dst[idx] = u;
        }
    }
    {   // V tile -> LDS transposed fp16
        const float4v* src = (const float4v*)(Vg + ((size_t)b * SEQ + s0) * DIM);
        #pragma unroll
        for (int j = 0; j < 8; ++j) {
            int f4 = j * 256 + t;
            int sl = f4 >> 5;
            int dc = (f4 & 31) * 4;
            float4v x = src[f4];
            unsigned int u01 = pkh(x[0], x[1]);
            unsigned int u23 = pkh(x[2], x[3]);
            Ts[(dc + 0) * VSTRP + sl] = (short)(u01 & 0xFFFFu);
            Ts[(dc + 1) * VSTRP + sl] = (short)(u01 >> 16);
            Ts[(dc + 2) * VSTRP + sl] = (short)(u23 & 0xFFFFu);
            Ts[(dc + 3) * VSTRP + sl] = (short)(u23 >> 16);
        }
    }
    __syncthreads();
    #pragma unroll
    for (int j = 0; j < 4; ++j) {
        int idx = j * 256 + t;                  // 1024 x 16B (128 d x 8 chunks)
        int d = idx >> 3;
        int c = idx & 7;
        uint4v val = *(const uint4v*)&Ts[d * VSTRP + c * 8];
        *(uint4v*)(VtG + ((size_t)b * DIM + d) * SEQ + s0 + c * 8) = val;
    }
}

// ---------------- main: 512-thr block = 4 wave-pairs over K-quarters; in-LDS combine ----------------
__global__ __launch_bounds__(512, 4)
void attn_fa3(const float* __restrict__ Qg, const short* __restrict__ Kh,
              const short* __restrict__ VtG, float* __restrict__ Og) {
    __shared__ char smem[4 * PAIR_LDS];   // 75776 B; epilogue aliases Obuf(33792)+Lbuf2(4096)

    const int t    = threadIdx.x;
    const int w    = t >> 6;
    const int lane = t & 63;
    const int pair = t >> 7;         // K-quarter 0..3
    const int tp   = t & 127;        // thread-in-pair
    const int e    = w & 1;          // wave-in-pair
    const int l15  = lane & 15;
    const int quad = lane >> 4;
    const int q8   = quad * 8;
    const int wq2  = e * 32;         // q-row base within 64-row tile

    short* Ks = (short*)(smem + pair * PAIR_LDS);
    short* Vt = (short*)(smem + pair * PAIR_LDS + BK * KSTR * 2);
    short* Ps = Ks;                  // aliased

    const int b     = blockIdx.x & 7;
    const int qbase = (blockIdx.x >> 3) * 64;
    const int kb0   = pair * (SEQ / 4);

    const float qs = 0.08838834764831845f * 1.44269504088896340f; // 1/sqrt(128)*log2(e)

    // Q fragments, register-resident
    half8 qf[2][4];
    {
        const float* Qb = Qg + ((size_t)b * SEQ + qbase + wq2) * DIM;
        #pragma unroll
        for (int m = 0; m < 2; ++m) {
            const float* qrow = Qb + (m * 16 + l15) * DIM;
            #pragma unroll
            for (int k = 0; k < 4; ++k) {
                float4v x0 = *(const float4v*)(qrow + k * 32 + q8);
                float4v x1 = *(const float4v*)(qrow + k * 32 + q8 + 4);
                uint4v u;
                u[0] = pkh(x0[0] * qs, x0[1] * qs);
                u[1] = pkh(x0[2] * qs, x0[3] * qs);
                u[2] = pkh(x1[0] * qs, x1[1] * qs);
                u[3] = pkh(x1[2] * qs, x1[3] * qs);
                qf[m][k] = __builtin_bit_cast(half8, u);
            }
        }
    }

    const float4v zero4 = {0.0f, 0.0f, 0.0f, 0.0f};
    float4v o_acc[2][8];
    float4v l_part[2];
    #pragma unroll
    for (int m = 0; m < 2; ++m) {
        l_part[m] = zero4;
        #pragma unroll
        for (int n = 0; n < 8; ++n) o_acc[m][n] = zero4;
    }

    const short* Khb = Kh + (size_t)b * SEQ * DIM;
    const short* Vtb = VtG + (size_t)b * DIM * SEQ;

    for (int kt = 0; kt < (SEQ / 4) / BK; ++kt) {
        const int kbase = kb0 + kt * BK;
        __syncthreads();   // prior PV reads of Ps/Vt done (pair-local; block barrier is uniform)

        // stage K quarter-tile 32x128 fp16: 512 x 16B / 128 thr
        {
            #pragma unroll
            for (int j = 0; j < 4; ++j) {
                int idx = j * 128 + tp;
                int row = idx >> 4;
                int c   = idx & 15;
                uint4v v = *(const uint4v*)(Khb + (size_t)(kbase + row) * DIM + c * 8);
                *(uint4v*)&Ks[row * KSTR + c * 8] = v;
            }
        }
        // stage Vt 128d x 32keys fp16: 512 x 16B / 128 thr
        {
            #pragma unroll
            for (int j = 0; j < 4; ++j) {
                int idx = j * 128 + tp;
                int d = idx >> 2;
                int c = idx & 3;
                uint4v v = *(const uint4v*)(Vtb + (size_t)d * SEQ + kbase + c * 8);
                *(uint4v*)&Vt[d * VSTR + c * 8] = v;
            }
        }
        __syncthreads();

        // S = Q K^T  (2 n-tiles of 16 keys)
        float4v s[2][2];
        #pragma unroll
        for (int m = 0; m < 2; ++m)
            #pragma unroll
            for (int nt = 0; nt < 2; ++nt) s[m][nt] = zero4;
        #pragma unroll
        for (int k = 0; k < 4; ++k) {
            #pragma unroll
            for (int nt = 0; nt < 2; ++nt) {
                half8 bk = *(const half8*)&Ks[(nt * 16 + l15) * KSTR + k * 32 + q8];
                s[0][nt] = __builtin_amdgcn_mfma_f32_16x16x32_f16(qf[0][k], bk, s[0][nt], 0, 0, 0);
                s[1][nt] = __builtin_amdgcn_mfma_f32_16x16x32_f16(qf[1][k], bk, s[1][nt], 0, 0, 0);
            }
        }
        __syncthreads();   // all pair waves done reading Ks before Ps overwrites it

        // P = exp2(S), partial l, stage P fp16
        #pragma unroll
        for (int m = 0; m < 2; ++m) {
            const int rowb = wq2 + m * 16 + quad * 4;
            #pragma unroll
            for (int nt = 0; nt < 2; ++nt) {
                const int colo = nt * 16 + l15;
                #pragma unroll
                for (int r = 0; r < 4; r += 2) {
                    float p0 = __builtin_amdgcn_exp2f(s[m][nt][r]);
                    float p1 = __builtin_amdgcn_exp2f(s[m][nt][r + 1]);
                    l_part[m][r]     += p0;
                    l_part[m][r + 1] += p1;
                    unsigned int u = pkh(p0, p1);
                    Ps[(rowb + r)     * PSTR + colo] = (short)(u & 0xFFFFu);
                    Ps[(rowb + r + 1) * PSTR + colo] = (short)(u >> 16);
                }
            }
        }
        // wave-local Ps round-trip (reads only rows this wave wrote)

        // O += P V  (single K=32 MFMA chunk)
        {
            half8 a0 = *(const half8*)&Ps[(wq2 + l15) * PSTR + q8];
            half8 a1 = *(const half8*)&Ps[(wq2 + 16 + l15) * PSTR + q8];
            #pragma unroll
            for (int nt2 = 0; nt2 < 8; ++nt2) {
                half8 bv = *(const half8*)&Vt[(nt2 * 16 + l15) * VSTR + q8];
                o_acc[0][nt2] = __builtin_amdgcn_mfma_f32_16x16x32_f16(a0, bv, o_acc[0][nt2], 0, 0, 0);
                o_acc[1][nt2] = __builtin_amdgcn_mfma_f32_16x16x32_f16(a1, bv, o_acc[1][nt2], 0, 0, 0);
            }
        }
    }

    // ---- in-LDS cross-pair combine: chain pair3 -> pair2 -> pair1 -> pair0 ----
    float* Obuf  = (float*)smem;                  // 64 x OSTR fp32 = 33792 B
    float* Lbuf2 = (float*)(smem + 64 * OSTR * 4); // 64 x 16 fp32 = 4096 B

    #pragma unroll
    for (int p = 3; p >= 1; --p) {
        __syncthreads();
        if (pair == p) {
            #pragma unroll
            for (int m = 0; m < 2; ++m) {
                const int rowb = wq2 + m * 16 + quad * 4;
                #pragma unroll
                for (int r = 0; r < 4; ++r) {
                    Lbuf2[(rowb + r) * 16 + l15] = l_part[m][r];
                    #pragma unroll
                    for (int nt2 = 0; nt2 < 8; ++nt2)
                        Obuf[(rowb + r) * OSTR + nt2 * 16 + l15] = o_acc[m][nt2][r];
                }
            }
        }
        __syncthreads();
        if (pair == p - 1) {
            #pragma unroll
            for (int m = 0; m < 2; ++m) {
                const int rowb = wq2 + m * 16 + quad * 4;
                #pragma unroll
                for (int r = 0; r < 4; ++r) {
                    l_part[m][r] += Lbuf2[(rowb + r) * 16 + l15];
                    #pragma unroll
                    for (int nt2 = 0; nt2 < 8; ++nt2)
                        o_acc[m][nt2][r] += Obuf[(rowb + r) * OSTR + nt2 * 16 + l15];
                }
            }
        }
    }

    // pair 0 holds totals: butterfly-reduce l over 16 lanes, normalize, store
    if (pair == 0) {
        #pragma unroll
        for (int m = 0; m < 2; ++m) {
            float4v l = l_part[m];
            #pragma unroll
            for (int off = 1; off <= 8; off <<= 1) {
                l[0] += __shfl_xor(l[0], off);
                l[1] += __shfl_xor(l[1], off);
                l[2] += __shfl_xor(l[2], off);
                l[3] += __shfl_xor(l[3], off);
            }
            float* Ob = Og + ((size_t)b * SEQ + qbase + wq2 + m * 16 + quad * 4) * DIM;
            #pragma unroll
            for (int r = 0; r < 4; ++r) {
                float inv = 1.0f / l[r];
                #pragma unroll
                for (int nt2 = 0; nt2 < 8; ++nt2)
                    Ob[r * DIM + nt2 * 16 + l15] = o_acc[m][nt2][r] * inv;
            }
        }
    }
}

extern "C" void kernel_launch(void* const* d_in, const int* in_sizes, int n_in,
                              void* d_out, int out_size, void* d_ws, size_t ws_size,
                              hipStream_t stream) {
    const float* Q = (const float*)d_in[0];
    const float* K = (const float*)d_in[1];
    const float* V = (const float*)d_in[2];
    float* O = (float*)d_out;
    char* ws = (char*)d_ws;
    short* Kh  = (short*)ws;
    short* VtG = (short*)(ws + VT_OFF);
    prepass<<<dim3(8 * (SEQ / 64)), dim3(256), 0, stream>>>(K, V, Kh, VtG);
    attn_fa3<<<dim3(8 * (SEQ / 64)), dim3(512), 0, stream>>>(Q, Kh, VtG, O);
}

// Round 6
// 286.614 us; speedup vs baseline: 1.2267x; 1.2267x over previous
//
#include <hip/hip_runtime.h>

#define SEQ 4096
#define DIM 128
#define BK 64
#define KSTR 136   // 128+8 fp16; row 272 B (16B-aligned, odd dword-quad factor)
#define VSTR 72    // 64+8;  row 144 B
#define PSTR 72
#define VSTRP 72   // prepass transpose tile stride
#define PAIR_LDS (BK * KSTR * 2 + DIM * VSTR * 2)   // 17408 + 18432 = 35840 B
#define OSTR 132   // epilogue Obuf stride (floats)

// workspace: fp16 K + fp16 V-transposed
#define KH_SZ  (8ull * SEQ * DIM * 2)
#define VT_OFF KH_SZ

typedef __attribute__((ext_vector_type(8))) _Float16 half8;
typedef __attribute__((ext_vector_type(2))) __fp16   fp16x2;
typedef __attribute__((ext_vector_type(4))) float  float4v;
typedef __attribute__((ext_vector_type(4))) unsigned int uint4v;

static __device__ __forceinline__ unsigned int pkh(float a, float b) {
    fp16x2 h = __builtin_amdgcn_cvt_pkrtz(a, b);
    return __builtin_bit_cast(unsigned int, h);
}

// ---------------- prepass: K -> fp16 [b][s][d], V -> fp16 transposed [b][d][s] ----------------
__global__ __launch_bounds__(256)
void prepass(const float* __restrict__ Kg, const float* __restrict__ Vg,
             short* __restrict__ Kh, short* __restrict__ VtG) {
    __shared__ short Ts[DIM * VSTRP];
    const int t  = threadIdx.x;
    const int b  = blockIdx.x & 7;
    const int s0 = (blockIdx.x >> 3) * 64;

    {   // K tile: 64 rows x 128 fp32 -> fp16
        const float4v* src = (const float4v*)(Kg + ((size_t)b * SEQ + s0) * DIM);
        uint4v* dst = (uint4v*)(Kh + ((size_t)b * SEQ + s0) * DIM);
        #pragma unroll
        for (int j = 0; j < 4; ++j) {
            int idx = j * 256 + t;
            float4v x0 = src[idx * 2];
            float4v x1 = src[idx * 2 + 1];
            uint4v u;
            u[0] = pkh(x0[0], x0[1]); u[1] = pkh(x0[2], x0[3]);
            u[2] = pkh(x1[0], x1[1]); u[3] = pkh(x1[2], x1[3]);
            dst[idx] = u;
        }
    }
    {   // V tile -> LDS transposed fp16
        const float4v* src = (const float4v*)(Vg + ((size_t)b * SEQ + s0) * DIM);
        #pragma unroll
        for (int j = 0; j < 8; ++j) {
            int f4 = j * 256 + t;
            int sl = f4 >> 5;
            int dc = (f4 & 31) * 4;
            float4v x = src[f4];
            unsigned int u01 = pkh(x[0], x[1]);
            unsigned int u23 = pkh(x[2], x[3]);
            Ts[(dc + 0) * VSTRP + sl] = (short)(u01 & 0xFFFFu);
            Ts[(dc + 1) * VSTRP + sl] = (short)(u01 >> 16);
            Ts[(dc + 2) * VSTRP + sl] = (short)(u23 & 0xFFFFu);
            Ts[(dc + 3) * VSTRP + sl] = (short)(u23 >> 16);
        }
    }
    __syncthreads();
    #pragma unroll
    for (int j = 0; j < 4; ++j) {
        int idx = j * 256 + t;                  // 1024 x 16B (128 d x 8 chunks)
        int d = idx >> 3;
        int c = idx & 7;
        uint4v val = *(const uint4v*)&Ts[d * VSTRP + c * 8];
        *(uint4v*)(VtG + ((size_t)b * DIM + d) * SEQ + s0 + c * 8) = val;
    }
}

// ---------------- main: 256-thr block = 2 pairs x 2 waves; in-block split-K x2 ----------------
__global__ __launch_bounds__(256, 2)
void attn_fa4(const float* __restrict__ Qg, const short* __restrict__ Kh,
              const short* __restrict__ VtG, float* __restrict__ Og) {
    __shared__ char smem[2 * PAIR_LDS];   // 71680 B; epilogue aliases Obuf+Lbuf at base

    const int t    = threadIdx.x;
    const int w    = t >> 6;         // wave 0..3
    const int lane = t & 63;
    const int pair = t >> 7;         // K-half 0/1
    const int tp   = t & 127;        // thread-in-pair
    const int e    = w & 1;          // wave-in-pair
    const int l15  = lane & 15;
    const int quad = lane >> 4;
    const int q8   = quad * 8;
    const int wq2  = e * 32;         // q-row base within 64-row tile

    short* Ks = (short*)(smem + pair * PAIR_LDS);
    short* Vt = (short*)(smem + pair * PAIR_LDS + BK * KSTR * 2);
    short* Ps = Ks;                  // aliased (guarded by post-QK barrier)

    const int b     = blockIdx.x & 7;               // XCD-sticky batch
    const int qbase = (blockIdx.x >> 3) * 64;
    const int kb0   = pair * (SEQ / 2);

    const float qs = 0.08838834764831845f * 1.44269504088896340f; // 1/sqrt(128)*log2(e)

    // Q fragments (pre-scaled fp16), register-resident
    half8 qf[2][4];
    {
        const float* Qb = Qg + ((size_t)b * SEQ + qbase + wq2) * DIM;
        #pragma unroll
        for (int m = 0; m < 2; ++m) {
            const float* qrow = Qb + (m * 16 + l15) * DIM;
            #pragma unroll
            for (int k = 0; k < 4; ++k) {
                float4v x0 = *(const float4v*)(qrow + k * 32 + q8);
                float4v x1 = *(const float4v*)(qrow + k * 32 + q8 + 4);
                uint4v u;
                u[0] = pkh(x0[0] * qs, x0[1] * qs);
                u[1] = pkh(x0[2] * qs, x0[3] * qs);
                u[2] = pkh(x1[0] * qs, x1[1] * qs);
                u[3] = pkh(x1[2] * qs, x1[3] * qs);
                qf[m][k] = __builtin_bit_cast(half8, u);
            }
        }
    }

    const float4v zero4 = {0.0f, 0.0f, 0.0f, 0.0f};
    float4v o_acc[2][8];
    float4v l_part[2];
    #pragma unroll
    for (int m = 0; m < 2; ++m) {
        l_part[m] = zero4;
        #pragma unroll
        for (int n = 0; n < 8; ++n) o_acc[m][n] = zero4;
    }

    const short* Khb = Kh + (size_t)b * SEQ * DIM;
    const short* Vtb = VtG + (size_t)b * DIM * SEQ;

    for (int kt = 0; kt < (SEQ / 2) / BK; ++kt) {
        const int kbase = kb0 + kt * BK;
        __syncthreads();   // prior PV reads of Ps/Vt done

        // stage K tile 64x128 fp16: 1024 x 16B over 128 pair-threads
        {
            #pragma unroll
            for (int j = 0; j < 8; ++j) {
                int idx = j * 128 + tp;
                int row = idx >> 4;
                int c   = idx & 15;
                uint4v v = *(const uint4v*)(Khb + (size_t)(kbase + row) * DIM + c * 8);
                *(uint4v*)&Ks[row * KSTR + c * 8] = v;
            }
        }
        // stage Vt 128d x 64keys fp16: 1024 x 16B over 128 pair-threads
        {
            #pragma unroll
            for (int j = 0; j < 8; ++j) {
                int idx = j * 128 + tp;
                int d = idx >> 3;
                int c = idx & 7;
                uint4v v = *(const uint4v*)(Vtb + (size_t)d * SEQ + kbase + c * 8);
                *(uint4v*)&Vt[d * VSTR + c * 8] = v;
            }
        }
        __syncthreads();

        // S = Q K^T  (4 n-tiles of 16 keys)
        float4v s[2][4];
        #pragma unroll
        for (int m = 0; m < 2; ++m)
            #pragma unroll
            for (int nt = 0; nt < 4; ++nt) s[m][nt] = zero4;
        #pragma unroll
        for (int k = 0; k < 4; ++k) {
            #pragma unroll
            for (int nt = 0; nt < 4; ++nt) {
                half8 bk = *(const half8*)&Ks[(nt * 16 + l15) * KSTR + k * 32 + q8];
                s[0][nt] = __builtin_amdgcn_mfma_f32_16x16x32_f16(qf[0][k], bk, s[0][nt], 0, 0, 0);
                s[1][nt] = __builtin_amdgcn_mfma_f32_16x16x32_f16(qf[1][k], bk, s[1][nt], 0, 0, 0);
            }
        }
        __syncthreads();   // all pair waves done reading Ks before Ps overwrites it

        // P = exp2(S), partial l, stage P fp16
        #pragma unroll
        for (int m = 0; m < 2; ++m) {
            const int rowb = wq2 + m * 16 + quad * 4;
            #pragma unroll
            for (int nt = 0; nt < 4; ++nt) {
                const int colo = nt * 16 + l15;
                #pragma unroll
                for (int r = 0; r < 4; r += 2) {
                    float p0 = __builtin_amdgcn_exp2f(s[m][nt][r]);
                    float p1 = __builtin_amdgcn_exp2f(s[m][nt][r + 1]);
                    l_part[m][r]     += p0;
                    l_part[m][r + 1] += p1;
                    unsigned int u = pkh(p0, p1);
                    Ps[(rowb + r)     * PSTR + colo] = (short)(u & 0xFFFFu);
                    Ps[(rowb + r + 1) * PSTR + colo] = (short)(u >> 16);
                }
            }
        }
        // wave-local Ps round-trip (reads only rows this wave wrote)

        // O += P V
        #pragma unroll
        for (int k2 = 0; k2 < 2; ++k2) {
            half8 a0 = *(const half8*)&Ps[(wq2 + l15) * PSTR + k2 * 32 + q8];
            half8 a1 = *(const half8*)&Ps[(wq2 + 16 + l15) * PSTR + k2 * 32 + q8];
            #pragma unroll
            for (int nt2 = 0; nt2 < 8; ++nt2) {
                half8 bv = *(const half8*)&Vt[(nt2 * 16 + l15) * VSTR + k2 * 32 + q8];
                o_acc[0][nt2] = __builtin_amdgcn_mfma_f32_16x16x32_f16(a0, bv, o_acc[0][nt2], 0, 0, 0);
                o_acc[1][nt2] = __builtin_amdgcn_mfma_f32_16x16x32_f16(a1, bv, o_acc[1][nt2], 0, 0, 0);
            }
        }
    }

    // ---- in-LDS cross-pair combine: pair1 -> pair0, then pair0 normalizes & stores ----
    float* Obuf = (float*)smem;                     // 64 x OSTR fp32 = 33792 B
    float* Lbuf = (float*)(smem + 64 * OSTR * 4);   // 64 x 16 fp32  =  4096 B

    __syncthreads();
    if (pair == 1) {
        #pragma unroll
        for (int m = 0; m < 2; ++m) {
            const int rowb = wq2 + m * 16 + quad * 4;
            #pragma unroll
            for (int r = 0; r < 4; ++r) {
                Lbuf[(rowb + r) * 16 + l15] = l_part[m][r];
                #pragma unroll
                for (int nt2 = 0; nt2 < 8; ++nt2)
                    Obuf[(rowb + r) * OSTR + nt2 * 16 + l15] = o_acc[m][nt2][r];
            }
        }
    }
    __syncthreads();
    if (pair == 0) {
        #pragma unroll
        for (int m = 0; m < 2; ++m) {
            const int rowb = wq2 + m * 16 + quad * 4;
            float4v l = l_part[m];
            #pragma unroll
            for (int r = 0; r < 4; ++r) {
                l[r] += Lbuf[(rowb + r) * 16 + l15];
                #pragma unroll
                for (int nt2 = 0; nt2 < 8; ++nt2)
                    o_acc[m][nt2][r] += Obuf[(rowb + r) * OSTR + nt2 * 16 + l15];
            }
            #pragma unroll
            for (int off = 1; off <= 8; off <<= 1) {
                l[0] += __shfl_xor(l[0], off);
                l[1] += __shfl_xor(l[1], off);
                l[2] += __shfl_xor(l[2], off);
                l[3] += __shfl_xor(l[3], off);
            }
            float* Ob = Og + ((size_t)b * SEQ + qbase + rowb) * DIM;
            #pragma unroll
            for (int r = 0; r < 4; ++r) {
                float inv = 1.0f / l[r];
                #pragma unroll
                for (int nt2 = 0; nt2 < 8; ++nt2)
                    Ob[r * DIM + nt2 * 16 + l15] = o_acc[m][nt2][r] * inv;
            }
        }
    }
}

extern "C" void kernel_launch(void* const* d_in, const int* in_sizes, int n_in,
                              void* d_out, int out_size, void* d_ws, size_t ws_size,
                              hipStream_t stream) {
    const float* Q = (const float*)d_in[0];
    const float* K = (const float*)d_in[1];
    const float* V = (const float*)d_in[2];
    float* O = (float*)d_out;
    char* ws = (char*)d_ws;
    short* Kh  = (short*)ws;
    short* VtG = (short*)(ws + VT_OFF);
    prepass<<<dim3(8 * (SEQ / 64)), dim3(256), 0, stream>>>(K, V, Kh, VtG);
    attn_fa4<<<dim3(8 * (SEQ / 64)), dim3(256), 0, stream>>>(Q, Kh, VtG, O);
}

// Round 7
// 191.378 us; speedup vs baseline: 1.8372x; 1.4976x over previous
//
#include <hip/hip_runtime.h>

#define SEQ 4096
#define DIM 128
#define BK 64
#define KSTR 136   // 128+8 fp16; row 272 B
#define VSTR 72    // 64+8;  row 144 B
#define PSTR 72
#define VSTRP 72   // prepass transpose tile stride (shorts)
#define NIT ((SEQ / 2) / BK)

// workspace layout (bytes)
#define KH_OFF 0ull
#define KH_SZ  (8ull * SEQ * DIM * 2)
#define VT_OFF (KH_OFF + KH_SZ)
#define VT_SZ  (8ull * SEQ * DIM * 2)
#define OP_OFF (VT_OFF + VT_SZ)
#define OP_SZ  (2ull * 8 * SEQ * DIM * 4)
#define LP_OFF (OP_OFF + OP_SZ)

typedef __attribute__((ext_vector_type(8))) _Float16 half8;
typedef __attribute__((ext_vector_type(2))) __fp16   fp16x2;
typedef __attribute__((ext_vector_type(4))) float  float4v;
typedef __attribute__((ext_vector_type(4))) unsigned int uint4v;
typedef __attribute__((ext_vector_type(2))) unsigned int uint2v;

static __device__ __forceinline__ unsigned int pkh(float a, float b) {
    fp16x2 h = __builtin_amdgcn_cvt_pkrtz(a, b);
    return __builtin_bit_cast(unsigned int, h);
}

// ---------------- prepass: K -> fp16 [b][s][d]; V -> fp16 transposed [b][d][s] ----------------
__global__ __launch_bounds__(256)
void prepass(const float* __restrict__ Kg, const float* __restrict__ Vg,
             short* __restrict__ Kh, short* __restrict__ VtG) {
    __shared__ short Ts[DIM * VSTRP];
    const int t  = threadIdx.x;
    const int b  = blockIdx.x & 7;
    const int s0 = (blockIdx.x >> 3) * 64;

    {   // K tile: 64 rows x 128 fp32 -> fp16, coalesced
        const float4v* src = (const float4v*)(Kg + ((size_t)b * SEQ + s0) * DIM);
        uint4v* dst = (uint4v*)(Kh + ((size_t)b * SEQ + s0) * DIM);
        #pragma unroll
        for (int j = 0; j < 4; ++j) {
            int idx = j * 256 + t;
            float4v x0 = src[idx * 2];
            float4v x1 = src[idx * 2 + 1];
            uint4v u;
            u[0] = pkh(x0[0], x0[1]); u[1] = pkh(x0[2], x0[3]);
            u[2] = pkh(x1[0], x1[1]); u[3] = pkh(x1[2], x1[3]);
            dst[idx] = u;
        }
    }
    {   // V tile: each thread 4 keys x 8 d -> Ts[d][key] (<=4-way conflicts, b64 writes)
        const int key4 = (t & 15) * 4;
        const int d0   = (t >> 4) * 8;
        const float* Vsrc = Vg + ((size_t)b * SEQ + s0) * DIM;
        float4v a[4][2];
        #pragma unroll
        for (int i = 0; i < 4; ++i) {
            a[i][0] = *(const float4v*)&Vsrc[(key4 + i) * DIM + d0];
            a[i][1] = *(const float4v*)&Vsrc[(key4 + i) * DIM + d0 + 4];
        }
        #pragma unroll
        for (int jj = 0; jj < 2; ++jj) {
            #pragma unroll
            for (int e = 0; e < 4; ++e) {
                int d = d0 + jj * 4 + e;
                uint2v pk;
                pk[0] = pkh(a[0][jj][e], a[1][jj][e]);
                pk[1] = pkh(a[2][jj][e], a[3][jj][e]);
                *(uint2v*)&Ts[d * VSTRP + key4] = pk;
            }
        }
    }
    __syncthreads();
    #pragma unroll
    for (int j = 0; j < 4; ++j) {
        int idx = j * 256 + t;                  // 1024 x 16B (128 d x 8 chunks)
        int d = idx >> 3;
        int c = idx & 7;
        uint4v val = *(const uint4v*)&Ts[d * VSTRP + c * 8];
        *(uint4v*)(VtG + ((size_t)b * DIM + d) * SEQ + s0 + c * 8) = val;
    }
}

// ---------------- main: 128-thr blocks, split-K x2, register-prefetched staging ----------------
__global__ __launch_bounds__(128, 2)
void attn_fa5(const float* __restrict__ Qg, const short* __restrict__ Kh,
              const short* __restrict__ VtG, float* __restrict__ Op,
              float* __restrict__ lp) {
    __shared__ short Ks[BK * KSTR];   // 17408 B; Ps aliased
    __shared__ short Vt[DIM * VSTR];  // 18432 B
    short* Ps = Ks;

    const int t    = threadIdx.x;
    const int w    = t >> 6;
    const int lane = t & 63;
    const int l15  = lane & 15;
    const int quad = lane >> 4;
    const int q8   = quad * 8;
    const int wq   = w * 32;

    // staging coords (fixed per thread)
    const int tr = t >> 4, tc = t & 15;   // K: rows j*8+tr, chunk tc
    const int td = t >> 3, vc = t & 7;    // V: d rows j*16+td, chunk vc

    const int b     = blockIdx.x & 7;
    const int half  = (blockIdx.x >> 3) & 1;
    const int qbase = (blockIdx.x >> 4) * 64;
    const int kb0   = half * (SEQ / 2);

    const float qs = 0.08838834764831845f * 1.44269504088896340f;

    // Q fragments (pre-scaled fp16), register-resident
    half8 qf[2][4];
    {
        const float* Qb = Qg + ((size_t)b * SEQ + qbase + wq) * DIM;
        #pragma unroll
        for (int m = 0; m < 2; ++m) {
            const float* qrow = Qb + (m * 16 + l15) * DIM;
            #pragma unroll
            for (int k = 0; k < 4; ++k) {
                float4v x0 = *(const float4v*)(qrow + k * 32 + q8);
                float4v x1 = *(const float4v*)(qrow + k * 32 + q8 + 4);
                uint4v u;
                u[0] = pkh(x0[0] * qs, x0[1] * qs);
                u[1] = pkh(x0[2] * qs, x0[3] * qs);
                u[2] = pkh(x1[0] * qs, x1[1] * qs);
                u[3] = pkh(x1[2] * qs, x1[3] * qs);
                qf[m][k] = __builtin_bit_cast(half8, u);
            }
        }
    }

    const float4v zero4 = {0.0f, 0.0f, 0.0f, 0.0f};
    float4v o_acc[2][8];
    float4v l_part[2];
    #pragma unroll
    for (int m = 0; m < 2; ++m) {
        l_part[m] = zero4;
        #pragma unroll
        for (int n = 0; n < 8; ++n) o_acc[m][n] = zero4;
    }

    const short* Khb = Kh + (size_t)b * SEQ * DIM;
    const short* Vtb = VtG + (size_t)b * DIM * SEQ;

    // ---- prefetch registers: iter-k+1 tiles live here during iter-k compute ----
    uint4v kpre[8], vpre[8];
    {
        const int kbase = kb0;
        #pragma unroll
        for (int j = 0; j < 8; ++j)
            kpre[j] = *(const uint4v*)(Khb + (size_t)(kbase + j * 8 + tr) * DIM + tc * 8);
        #pragma unroll
        for (int j = 0; j < 8; ++j)
            vpre[j] = *(const uint4v*)(Vtb + (size_t)(j * 16 + td) * SEQ + kbase + vc * 8);
    }

    for (int kt = 0; kt < NIT; ++kt) {
        __syncthreads();   // prior iter's Ks/Ps/Vt reads complete

        // write prefetched tiles to LDS
        #pragma unroll
        for (int j = 0; j < 8; ++j)
            *(uint4v*)&Ks[(j * 8 + tr) * KSTR + tc * 8] = kpre[j];
        #pragma unroll
        for (int j = 0; j < 8; ++j)
            *(uint4v*)&Vt[(j * 16 + td) * VSTR + vc * 8] = vpre[j];
        __syncthreads();

        // issue next iter's global loads (latency hidden behind compute below)
        if (kt + 1 < NIT) {
            const int kbase = kb0 + (kt + 1) * BK;
            #pragma unroll
            for (int j = 0; j < 8; ++j)
                kpre[j] = *(const uint4v*)(Khb + (size_t)(kbase + j * 8 + tr) * DIM + tc * 8);
            #pragma unroll
            for (int j = 0; j < 8; ++j)
                vpre[j] = *(const uint4v*)(Vtb + (size_t)(j * 16 + td) * SEQ + kbase + vc * 8);
        }

        // S = Q K^T
        float4v s[2][4];
        #pragma unroll
        for (int m = 0; m < 2; ++m)
            #pragma unroll
            for (int nt = 0; nt < 4; ++nt) s[m][nt] = zero4;
        #pragma unroll
        for (int k = 0; k < 4; ++k) {
            #pragma unroll
            for (int nt = 0; nt < 4; ++nt) {
                half8 bk = *(const half8*)&Ks[(nt * 16 + l15) * KSTR + k * 32 + q8];
                s[0][nt] = __builtin_amdgcn_mfma_f32_16x16x32_f16(qf[0][k], bk, s[0][nt], 0, 0, 0);
                s[1][nt] = __builtin_amdgcn_mfma_f32_16x16x32_f16(qf[1][k], bk, s[1][nt], 0, 0, 0);
            }
        }
        __syncthreads();   // all waves done reading Ks before Ps overwrites it

        // P = exp2(S), partial l, stage P fp16
        #pragma unroll
        for (int m = 0; m < 2; ++m) {
            const int rowb = wq + m * 16 + quad * 4;
            #pragma unroll
            for (int nt = 0; nt < 4; ++nt) {
                const int colo = nt * 16 + l15;
                #pragma unroll
                for (int r = 0; r < 4; r += 2) {
                    float p0 = __builtin_amdgcn_exp2f(s[m][nt][r]);
                    float p1 = __builtin_amdgcn_exp2f(s[m][nt][r + 1]);
                    l_part[m][r]     += p0;
                    l_part[m][r + 1] += p1;
                    unsigned int u = pkh(p0, p1);
                    Ps[(rowb + r)     * PSTR + colo] = (short)(u & 0xFFFFu);
                    Ps[(rowb + r + 1) * PSTR + colo] = (short)(u >> 16);
                }
            }
        }
        // wave-local Ps round-trip (reads only rows this wave wrote)

        // O += P V
        #pragma unroll
        for (int k2 = 0; k2 < 2; ++k2) {
            half8 a0 = *(const half8*)&Ps[(wq + l15) * PSTR + k2 * 32 + q8];
            half8 a1 = *(const half8*)&Ps[(wq + 16 + l15) * PSTR + k2 * 32 + q8];
            #pragma unroll
            for (int nt2 = 0; nt2 < 8; ++nt2) {
                half8 bv = *(const half8*)&Vt[(nt2 * 16 + l15) * VSTR + k2 * 32 + q8];
                o_acc[0][nt2] = __builtin_amdgcn_mfma_f32_16x16x32_f16(a0, bv, o_acc[0][nt2], 0, 0, 0);
                o_acc[1][nt2] = __builtin_amdgcn_mfma_f32_16x16x32_f16(a1, bv, o_acc[1][nt2], 0, 0, 0);
            }
        }
    }

    // epilogue: reduce l over 16 lanes, store UNNORMALIZED partials + l
    #pragma unroll
    for (int m = 0; m < 2; ++m) {
        float4v l = l_part[m];
        #pragma unroll
        for (int off = 1; off <= 8; off <<= 1) {
            l[0] += __shfl_xor(l[0], off);
            l[1] += __shfl_xor(l[1], off);
            l[2] += __shfl_xor(l[2], off);
            l[3] += __shfl_xor(l[3], off);
        }
        const int row0 = qbase + wq + m * 16 + quad * 4;
        float* Ob = Op + (((size_t)half * 8 + b) * SEQ + row0) * DIM;
        #pragma unroll
        for (int r = 0; r < 4; ++r) {
            #pragma unroll
            for (int nt2 = 0; nt2 < 8; ++nt2)
                Ob[r * DIM + nt2 * 16 + l15] = o_acc[m][nt2][r];
        }
        if (l15 == 0) {
            #pragma unroll
            for (int r = 0; r < 4; ++r)
                lp[((size_t)half * 8 + b) * SEQ + row0 + r] = l[r];
        }
    }
}

// ---------------- combine: O = (n0+n1)/(l0+l1) ----------------
__global__ __launch_bounds__(256)
void combine(const float4v* __restrict__ Op, const float* __restrict__ lp,
             float4v* __restrict__ Out) {
    const size_t idx = (size_t)blockIdx.x * 256 + threadIdx.x;   // float4 units
    const size_t srow = idx >> 5;                                // (b*SEQ + q)
    float l = lp[srow] + lp[srow + 8 * SEQ];
    float inv = 1.0f / l;
    float4v n0 = Op[idx];
    float4v n1 = Op[idx + 8ull * SEQ * DIM / 4];
    float4v o;
    o[0] = (n0[0] + n1[0]) * inv;
    o[1] = (n0[1] + n1[1]) * inv;
    o[2] = (n0[2] + n1[2]) * inv;
    o[3] = (n0[3] + n1[3]) * inv;
    Out[idx] = o;
}

extern "C" void kernel_launch(void* const* d_in, const int* in_sizes, int n_in,
                              void* d_out, int out_size, void* d_ws, size_t ws_size,
                              hipStream_t stream) {
    const float* Q = (const float*)d_in[0];
    const float* K = (const float*)d_in[1];
    const float* V = (const float*)d_in[2];
    float* O = (float*)d_out;
    char* ws = (char*)d_ws;
    short* Kh  = (short*)(ws + KH_OFF);
    short* VtG = (short*)(ws + VT_OFF);
    float* Op  = (float*)(ws + OP_OFF);
    float* lp  = (float*)(ws + LP_OFF);
    prepass<<<dim3(8 * (SEQ / 64)), dim3(256), 0, stream>>>(K, V, Kh, VtG);
    attn_fa5<<<dim3(8 * 2 * (SEQ / 64)), dim3(128), 0, stream>>>(Q, Kh, VtG, Op, lp);
    combine<<<dim3((8 * SEQ * DIM / 4) / 256), dim3(256), 0, stream>>>(
        (const float4v*)Op, lp, (float4v*)O);
}